// Round 4
// baseline (2739.552 us; speedup 1.0000x reference)
//
#include <hip/hip_runtime.h>

typedef unsigned short u16;
typedef unsigned int   u32;
typedef float  f32x4  __attribute__((ext_vector_type(4)));
typedef __bf16 bf16x8 __attribute__((ext_vector_type(8)));
typedef u32    u32x4  __attribute__((ext_vector_type(4)));
typedef u32    u32x2  __attribute__((ext_vector_type(2)));

#define Bb  8
#define Nn  1024
#define Dd  256
#define Hh  8
#define HDd 32

__device__ __forceinline__ u16 f2bf(float f){
  u32 u; __builtin_memcpy(&u, &f, 4);
  u = (u + 0x7fffu + ((u >> 16) & 1u)) >> 16;
  return (u16)u;
}
__device__ __forceinline__ f32x4 mfma16(bf16x8 a, bf16x8 b, f32x4 c){
  return __builtin_amdgcn_mfma_f32_16x16x32_bf16(a, b, c, 0, 0, 0);
}
__device__ __forceinline__ bf16x8 ld_bf8(const u16* p){
  u32x4 u = *(const u32x4*)p; bf16x8 r; __builtin_memcpy(&r, &u, 16); return r;
}

// ---------------- 256x256 transpose: Wt[k][e] = W[e][k] ----------------
__global__ void transpose256(const float* __restrict__ W, float* __restrict__ Wt){
  int e = blockIdx.x, k = threadIdx.x;
  Wt[(long)k * 256 + e] = W[(long)e * 256 + k];
}

// ---------------- naive projection: C[r][e] = sum_k A[r][k]*Wt[k][e] + bias[e] ----------------
__global__ __launch_bounds__(256) void proj_f32(
    const float* __restrict__ A, const float* __restrict__ Wt,
    const float* __restrict__ bias, float* __restrict__ C)
{
  __shared__ float a[4][256];
  const int r0 = blockIdx.x * 4, t = threadIdx.x;
  #pragma unroll
  for (int i = 0; i < 4; ++i)
    a[i][t] = A[(long)(r0 + i) * 256 + t];
  __syncthreads();
  float acc[4] = {0.f, 0.f, 0.f, 0.f};
  for (int k = 0; k < 256; ++k){
    float w = Wt[(long)k * 256 + t];
    #pragma unroll
    for (int i = 0; i < 4; ++i) acc[i] += a[i][k] * w;
  }
  float b = bias ? bias[t] : 0.f;
  #pragma unroll
  for (int i = 0; i < 4; ++i)
    C[(long)(r0 + i) * 256 + t] = acc[i] + b;
}

// ---------------- naive attention: one block per (b, row i), pure f32 VALU ----------------
__global__ __launch_bounds__(256) void attn_naive(
    const float* __restrict__ qf, const float* __restrict__ kf,
    const float* __restrict__ vf, const float* __restrict__ adj,
    float* __restrict__ of, u16* __restrict__ am, int transposed)
{
  __shared__ float qs[256];
  __shared__ float S[1024];
  __shared__ float red[256];
  __shared__ unsigned char msk[1024];
  const int b = blockIdx.y, i = blockIdx.x, t = threadIdx.x;
  const float SCALE = 0.17677669529663687f;  // 1/sqrt(32)
  qs[t] = qf[((long)b * Nn + i) * Dd + t];
  #pragma unroll
  for (int c = 0; c < 4; ++c){
    int j = t + 256 * c;
    msk[j] = (adj[(long)i * Nn + j] != 0.f) ? 1 : 0;
  }
  __syncthreads();
  float amreg[4] = {0.f, 0.f, 0.f, 0.f};
  for (int h = 0; h < Hh; ++h){
    // ---- scores for this thread's 4 columns ----
    float sv[4]; float mx = -3.0e38f;
    #pragma unroll
    for (int c = 0; c < 4; ++c){
      int j = t + 256 * c;
      float s = -3.0e38f;
      if (msk[j]){
        s = 0.f;
        const float* kp = kf + ((long)b * Nn + j) * Dd + h * HDd;
        #pragma unroll
        for (int d = 0; d < HDd; ++d) s += qs[h * HDd + d] * kp[d];
        s *= SCALE;
        mx = fmaxf(mx, s);
      }
      sv[c] = s;
    }
    // ---- block max ----
    red[t] = mx; __syncthreads();
    for (int off = 128; off; off >>= 1){
      if (t < off) red[t] = fmaxf(red[t], red[t + off]);
      __syncthreads();
    }
    float m = red[0]; __syncthreads();
    // ---- exp + block sum ----
    float l = 0.f;
    #pragma unroll
    for (int c = 0; c < 4; ++c){
      int j = t + 256 * c;
      float e = msk[j] ? __expf(sv[c] - m) : 0.f;
      S[j] = e; l += e;
    }
    red[t] = l; __syncthreads();
    for (int off = 128; off; off >>= 1){
      if (t < off) red[t] += red[t + off];
      __syncthreads();
    }
    float invl = 1.f / red[0]; __syncthreads();
    // ---- head-averaged attention accumulate ----
    #pragma unroll
    for (int c = 0; c < 4; ++c) amreg[c] += S[t + 256 * c] * invl * 0.125f;
    // ---- PV: thread (hd = t&31, chunk = t>>5) ----
    const int hd = t & 31, c2 = t >> 5;
    float acc = 0.f;
    const float* vp = vf + (long)b * Nn * Dd + h * HDd + hd;
    for (int j = c2 * 128; j < c2 * 128 + 128; ++j){
      float e = S[j];
      if (e != 0.f) acc += e * vp[(long)j * Dd];
    }
    red[t] = acc; __syncthreads();
    if (t < 32){
      float s = 0.f;
      #pragma unroll
      for (int cc = 0; cc < 8; ++cc) s += red[t + 32 * cc];
      of[((long)b * Nn + i) * Dd + h * HDd + t] = s * invl;
    }
    __syncthreads();
  }
  // ---- write head-averaged attention (bf16 scratch for chain GEMMs) ----
  if (!transposed){
    u16* dst = am + (long)b * Nn * Nn + (long)i * Nn;
    #pragma unroll
    for (int c = 0; c < 4; ++c) dst[t + 256 * c] = f2bf(amreg[c]);
  } else {
    u16* dst = am + (long)b * Nn * Nn + i;
    #pragma unroll
    for (int c = 0; c < 4; ++c) dst[(long)(t + 256 * c) * Nn] = f2bf(amreg[c]);
  }
}

// ---------------- residual + layernorm (f32; optional f32 copy to d_out) ----------------
__global__ __launch_bounds__(256) void ln_f32(
    const float* __restrict__ hin, const float* __restrict__ y,
    float* __restrict__ hout, float* __restrict__ outf,
    const float* __restrict__ g, const float* __restrict__ be)
{
  int row  = blockIdx.x * 4 + (threadIdx.x >> 6);
  int lane = threadIdx.x & 63;
  f32x4 v = *(const f32x4*)(hin + (long)row * Dd + lane * 4)
          + *(const f32x4*)(y   + (long)row * Dd + lane * 4);
  float s = v[0] + v[1] + v[2] + v[3];
  #pragma unroll
  for (int off = 32; off; off >>= 1) s += __shfl_xor(s, off, 64);
  float mu = s * (1.f / 256.f);
  f32x4 d = v - mu;
  float q2 = d[0]*d[0] + d[1]*d[1] + d[2]*d[2] + d[3]*d[3];
  #pragma unroll
  for (int off = 32; off; off >>= 1) q2 += __shfl_xor(q2, off, 64);
  float rs = rsqrtf(q2 * (1.f / 256.f) + 1e-5f);
  f32x4 ov;
  #pragma unroll
  for (int p = 0; p < 4; ++p)
    ov[p] = d[p] * rs * g[lane*4 + p] + be[lane*4 + p];
  *(f32x4*)(hout + (long)row * Dd + lane * 4) = ov;
  if (outf)
    *(f32x4*)(outf + (long)row * Dd + lane * 4) = ov;
}

// ---------------- MFMA GEMM: C[m][n] = sum_k A[m][k]*Bt[n][k] ----------------
template<bool HBC, bool HBR, bool OF, bool OB>
__global__ __launch_bounds__(256,2) void gemm_bt(
    const u16* __restrict__ A, int lda, long sA,
    const u16* __restrict__ Bt, int ldb, long sB,
    float* __restrict__ Cf, u16* __restrict__ Cb, int ldc, long sC,
    int K, const float* __restrict__ bc, const float* __restrict__ br)
{
  __shared__ u16 As[128][40];
  __shared__ u16 Bs[128][40];
  const int bz = blockIdx.z;
  const u16* Ap = A + (long)bz * sA;
  const u16* Bp = Bt + (long)bz * sB;
  const long co = (long)bz * sC;
  const int m0 = blockIdx.y * 128, n0 = blockIdx.x * 128;
  const int tid = threadIdx.x, wave = tid >> 6, lane = tid & 63;
  const int arow = lane & 15, agrp = lane >> 4;
  const int wr = (wave >> 1) * 64, wc = (wave & 1) * 64;
  const int srow = tid >> 1, sch = (tid & 1) * 16;
  const u16* ga = Ap + (long)(m0 + srow) * lda + sch;
  const u16* gb = Bp + (long)(n0 + srow) * ldb + sch;
  f32x4 acc[4][4] = {};
  for (int kb = 0; kb < K; kb += 32){
    u32x4 a0 = *(const u32x4*)ga; u32x4 a1 = *(const u32x4*)(ga + 8);
    u32x4 b0 = *(const u32x4*)gb; u32x4 b1 = *(const u32x4*)(gb + 8);
    __syncthreads();
    *(u32x4*)&As[srow][sch] = a0; *(u32x4*)&As[srow][sch + 8] = a1;
    *(u32x4*)&Bs[srow][sch] = b0; *(u32x4*)&Bs[srow][sch + 8] = b1;
    __syncthreads();
    ga += 32; gb += 32;
    bf16x8 af[4], bv[4];
    #pragma unroll
    for (int f = 0; f < 4; ++f){
      af[f] = ld_bf8(&As[wr + f*16 + arow][agrp*8]);
      bv[f] = ld_bf8(&Bs[wc + f*16 + arow][agrp*8]);
    }
    #pragma unroll
    for (int fm = 0; fm < 4; ++fm)
      #pragma unroll
      for (int fn = 0; fn < 4; ++fn)
        acc[fm][fn] = mfma16(af[fm], bv[fn], acc[fm][fn]);
  }
  #pragma unroll
  for (int fm = 0; fm < 4; ++fm){
    #pragma unroll
    for (int fn = 0; fn < 4; ++fn){
      int j = n0 + wc + fn*16 + arow;
      float badd = 0.f;
      if (HBC) badd = bc[j];
      #pragma unroll
      for (int r = 0; r < 4; ++r){
        int i = m0 + wr + fm*16 + agrp*4 + r;
        float v = acc[fm][fn][r] + badd;
        if (HBR) v += br[i];
        long idx = co + (long)i * ldc + j;
        if (OF) Cf[idx] = v;
        if (OB) Cb[idx] = f2bf(v);
      }
    }
  }
}

extern "C" void kernel_launch(void* const* d_in, const int* in_sizes, int n_in,
                              void* d_out, int out_size, void* d_ws, size_t ws_size,
                              hipStream_t stream)
{
  (void)in_sizes; (void)n_in; (void)out_size; (void)ws_size;
  const float* x   = (const float*)d_in[0];
  const float* adj = (const float*)d_in[1];
  const float* W0  = (const float*)d_in[2];
  const float* Wq  = (const float*)d_in[3];
  const float* bq  = (const float*)d_in[4];
  const float* Wk  = (const float*)d_in[5];
  const float* bk  = (const float*)d_in[6];
  const float* Wv  = (const float*)d_in[7];
  const float* bv  = (const float*)d_in[8];
  const float* Wo  = (const float*)d_in[9];
  const float* bo  = (const float*)d_in[10];
  const float* gm  = (const float*)d_in[11];
  const float* bt  = (const float*)d_in[12];
  float* outf  = (float*)d_out;                 // f32! h region [8,1024,256]
  float* outat = outf + (long)Bb * Nn * Dd;     // f32 atten region [8,1024,1024]
  const long NN = (long)Nn * Nn;

  // ---- workspace (~92MB, h-path first) ----
  char* w = (char*)d_ws;
  float* Wt = (float*)w; w += 13L * 65536 * 4;   // [13][256][256] transposed weights
  float* hf = (float*)w; w += 8388608;
  float* qf = (float*)w; w += 8388608;           // also reused as yf
  float* kf = (float*)w; w += 8388608;
  float* vf = (float*)w; w += 8388608;
  float* of = (float*)w; w += 8388608;
  u16* amA  = (u16*)w;  w += 16777216;           // am0^T, later am2
  u16* amB  = (u16*)w;  w += 16777216;           // am1
  u16* amC  = (u16*)w;  w += 16777216;           // P1^T

  dim3 blk(256);
  // transpose all weights: slot 0 = W0, 1-3 = Wq, 4-6 = Wk, 7-9 = Wv, 10-12 = Wo
  transpose256<<<256, blk, 0, stream>>>(W0, Wt);
  for (int l = 0; l < 3; ++l){
    transpose256<<<256, blk, 0, stream>>>(Wq + (long)l*65536, Wt + (long)(1+l)*65536);
    transpose256<<<256, blk, 0, stream>>>(Wk + (long)l*65536, Wt + (long)(4+l)*65536);
    transpose256<<<256, blk, 0, stream>>>(Wv + (long)l*65536, Wt + (long)(7+l)*65536);
    transpose256<<<256, blk, 0, stream>>>(Wo + (long)l*65536, Wt + (long)(10+l)*65536);
  }

  // input projection: h = x @ W0^T (no bias)
  proj_f32<<<2048, blk, 0, stream>>>(x, Wt, nullptr, hf);

  for (int l = 0; l < 3; ++l){
    proj_f32<<<2048, blk, 0, stream>>>(hf, Wt + (long)(1+l)*65536, bq + l*256, qf);
    proj_f32<<<2048, blk, 0, stream>>>(hf, Wt + (long)(4+l)*65536, bk + l*256, kf);
    proj_f32<<<2048, blk, 0, stream>>>(hf, Wt + (long)(7+l)*65536, bv + l*256, vf);
    attn_naive<<<dim3(Nn, Bb), blk, 0, stream>>>(
        qf, kf, vf, adj, of, (l == 0 ? amA : (l == 1 ? amB : amA)), (l == 0) ? 1 : 0);
    // y = o @ Wo^T + bo  (into qf, which is dead until next layer's q-proj)
    proj_f32<<<2048, blk, 0, stream>>>(of, Wt + (long)(10+l)*65536, bo + l*256, qf);
    ln_f32<<<2048, blk, 0, stream>>>(
        hf, qf, hf, (l < 2 ? nullptr : outf), gm + l*256, bt + l*256);
    // ---- chain (MFMA gemm_bt) ----
    // l1: P1^T[i][j] = sum_k am0T[i,k]*am1[j,k]  -> amC (bf16)
    // l2: final[i][j] = sum_k am2[i,k]*P1T[j,k] = (am2 @ P1)[i][j] -> f32 d_out
    if (l == 1)
      gemm_bt<false,false,false,true><<<dim3(8,8,8), blk, 0, stream>>>(
          amA, 1024, NN, amB, 1024, NN, nullptr, amC, 1024, NN, 1024, nullptr, nullptr);
    if (l == 2)
      gemm_bt<false,false,true,false><<<dim3(8,8,8), blk, 0, stream>>>(
          amA, 1024, NN, amC, 1024, NN, outat, nullptr, 1024, NN, 1024, nullptr, nullptr);
  }
}

// Round 5
// 700.538 us; speedup vs baseline: 3.9106x; 3.9106x over previous
//
#include <hip/hip_runtime.h>

typedef unsigned short u16;
typedef unsigned int   u32;
typedef float  f32x4  __attribute__((ext_vector_type(4)));
typedef __bf16 bf16x8 __attribute__((ext_vector_type(8)));
typedef u32    u32x4  __attribute__((ext_vector_type(4)));
typedef u32    u32x2  __attribute__((ext_vector_type(2)));

#define Bb  8
#define Nn  1024
#define Dd  256
#define Hh  8
#define HDd 32

__device__ __forceinline__ u16 f2bf(float f){
  u32 u; __builtin_memcpy(&u, &f, 4);
  u = (u + 0x7fffu + ((u >> 16) & 1u)) >> 16;
  return (u16)u;
}
__device__ __forceinline__ f32x4 mfma16(bf16x8 a, bf16x8 b, f32x4 c){
  return __builtin_amdgcn_mfma_f32_16x16x32_bf16(a, b, c, 0, 0, 0);
}
__device__ __forceinline__ bf16x8 ld_bf8(const u16* p){
  u32x4 u = *(const u32x4*)p; bf16x8 r; __builtin_memcpy(&r, &u, 16); return r;
}

// ---------------- f32 -> bf16 convert ----------------
__global__ void f32_to_bf16(const float* __restrict__ src, u16* __restrict__ dst, int n){
  int i = (blockIdx.x * 256 + threadIdx.x) * 4;
  if (i < n){
    f32x4 v = *(const f32x4*)(src + i);
    u32x2 p;
    p[0] = (u32)f2bf(v[0]) | ((u32)f2bf(v[1]) << 16);
    p[1] = (u32)f2bf(v[2]) | ((u32)f2bf(v[3]) << 16);
    *(u32x2*)(dst + i) = p;
  }
}

// ---------------- adj -> bitmask ----------------
__global__ void adj_to_bits(const float* __restrict__ adj, u32* __restrict__ bits){
  int w = blockIdx.x * 256 + threadIdx.x;        // word over [1024][32]
  const float* p = adj + (long)w * 32;
  u32 m = 0;
  #pragma unroll
  for (int t = 0; t < 32; t += 4){
    f32x4 v = *(const f32x4*)(p + t);
    if (v[0] != 0.f) m |= 1u << (t+0);
    if (v[1] != 0.f) m |= 1u << (t+1);
    if (v[2] != 0.f) m |= 1u << (t+2);
    if (v[3] != 0.f) m |= 1u << (t+3);
  }
  bits[w] = m;
}

// ---------------- MFMA GEMM: C[m][n] = sum_k A[m][k]*Bt[n][k] (+bias) ----------------
// VALIDATED (R4): bf16 and f32 epilogues both correct.
template<bool HBC, bool HBR, bool OF, bool OB>
__global__ __launch_bounds__(256,2) void gemm_bt(
    const u16* __restrict__ A, int lda, long sA,
    const u16* __restrict__ Bt, int ldb, long sB,
    float* __restrict__ Cf, u16* __restrict__ Cb, int ldc, long sC,
    int K, const float* __restrict__ bc, const float* __restrict__ br)
{
  __shared__ u16 As[128][40];
  __shared__ u16 Bs[128][40];
  const int bz = blockIdx.z;
  const u16* Ap = A + (long)bz * sA;
  const u16* Bp = Bt + (long)bz * sB;
  const long co = (long)bz * sC;
  const int m0 = blockIdx.y * 128, n0 = blockIdx.x * 128;
  const int tid = threadIdx.x, wave = tid >> 6, lane = tid & 63;
  const int arow = lane & 15, agrp = lane >> 4;
  const int wr = (wave >> 1) * 64, wc = (wave & 1) * 64;
  const int srow = tid >> 1, sch = (tid & 1) * 16;
  const u16* ga = Ap + (long)(m0 + srow) * lda + sch;
  const u16* gb = Bp + (long)(n0 + srow) * ldb + sch;
  f32x4 acc[4][4] = {};
  for (int kb = 0; kb < K; kb += 32){
    u32x4 a0 = *(const u32x4*)ga; u32x4 a1 = *(const u32x4*)(ga + 8);
    u32x4 b0 = *(const u32x4*)gb; u32x4 b1 = *(const u32x4*)(gb + 8);
    __syncthreads();
    *(u32x4*)&As[srow][sch] = a0; *(u32x4*)&As[srow][sch + 8] = a1;
    *(u32x4*)&Bs[srow][sch] = b0; *(u32x4*)&Bs[srow][sch + 8] = b1;
    __syncthreads();
    ga += 32; gb += 32;
    bf16x8 af[4], bv[4];
    #pragma unroll
    for (int f = 0; f < 4; ++f){
      af[f] = ld_bf8(&As[wr + f*16 + arow][agrp*8]);
      bv[f] = ld_bf8(&Bs[wc + f*16 + arow][agrp*8]);
    }
    #pragma unroll
    for (int fm = 0; fm < 4; ++fm)
      #pragma unroll
      for (int fn = 0; fn < 4; ++fn)
        acc[fm][fn] = mfma16(af[fm], bv[fn], acc[fm][fn]);
  }
  #pragma unroll
  for (int fm = 0; fm < 4; ++fm){
    #pragma unroll
    for (int fn = 0; fn < 4; ++fn){
      int j = n0 + wc + fn*16 + arow;
      float badd = 0.f;
      if (HBC) badd = bc[j];
      #pragma unroll
      for (int r = 0; r < 4; ++r){
        int i = m0 + wr + fm*16 + agrp*4 + r;
        float v = acc[fm][fn][r] + badd;
        if (HBR) v += br[i];
        long idx = co + (long)i * ldc + j;
        if (OF) Cf[idx] = v;
        if (OB) Cb[idx] = f2bf(v);
      }
    }
  }
}

// ---------------- fused masked attention (per b, 16-row tile, all heads) ----------------
#define NPAD 1036
__global__ __launch_bounds__(512,2) void attn_kernel(
    const u16* __restrict__ q, const u16* __restrict__ k,
    const u16* __restrict__ vT, u16* __restrict__ o,
    const u32* __restrict__ bitsg, u16* __restrict__ am, int transposed)
{
  __shared__ float S[16][NPAD];      // scores -> exp values
  __shared__ float AM[16][NPAD];     // head-averaged attention accumulator
  __shared__ u16   qs[16][264];
  __shared__ u32   bits[16][32];
  __shared__ float Lr[16];

  const int b = blockIdx.y, i0 = blockIdx.x * 16;
  const int tid = threadIdx.x, wave = tid >> 6, lane = tid & 63;
  const int arow = lane & 15, agrp = lane >> 4;
  const float SCALE = 0.17677669529663687f;   // 1/sqrt(32)
  const u16* qp = q  + ((long)b * Nn + i0) * Dd;
  const u16* kp = k  + (long)b * Nn * Dd;
  const u16* vp = vT + (long)b * Dd * Nn;

  { int r = tid >> 5, c = (tid & 31) * 8;
    *(u32x4*)&qs[r][c] = *(const u32x4*)(qp + (long)r * Dd + c); }
  { int r = tid >> 5, w = tid & 31;
    bits[r][w] = bitsg[(long)(i0 + r) * 32 + w]; }
  { float* amf = &AM[0][0];
    for (int idx = tid; idx < 16 * NPAD; idx += 512) amf[idx] = 0.f; }

  const f32x4 zacc = {0.f, 0.f, 0.f, 0.f};

  for (int h = 0; h < Hh; ++h){
    __syncthreads();                       // protect S refill vs prev consumers
    // ---- S fill: wave covers 8 j-tiles of 16 ----
    bf16x8 afr = ld_bf8(&qs[arow][h * HDd + agrp * 8]);
    #pragma unroll
    for (int s = 0; s < 8; ++s){
      int j0 = (wave * 8 + s) * 16;
      bf16x8 bfr = ld_bf8(kp + (long)(j0 + arow) * Dd + h * HDd + agrp * 8);
      f32x4 c = mfma16(afr, bfr, zacc);
      #pragma unroll
      for (int r = 0; r < 4; ++r) S[agrp*4 + r][j0 + arow] = c[r] * SCALE;
    }
    __syncthreads();
    // ---- masked softmax (32 threads / row) ----
    { int r = tid >> 5, jl = tid & 31;
      float m = -3e38f;
      for (int it = 0; it < 32; ++it){
        u32 bw = bits[r][it];
        if ((bw >> jl) & 1u) m = fmaxf(m, S[r][jl + it*32]);
      }
      #pragma unroll
      for (int off = 16; off; off >>= 1) m = fmaxf(m, __shfl_xor(m, off, 32));
      float l = 0.f;
      for (int it = 0; it < 32; ++it){
        int j = jl + it*32;
        u32 bw = bits[r][it];
        float sv = S[r][j];
        float e = ((bw >> jl) & 1u) ? __expf(sv - m) : 0.f;
        S[r][j] = e; l += e;
      }
      #pragma unroll
      for (int off = 16; off; off >>= 1) l += __shfl_xor(l, off, 32);
      if (jl == 0) Lr[r] = l;
    }
    __syncthreads();
    // ---- a_mean accumulate (zero-skip; thread-private chunks) ----
    { int r = tid >> 5, jl = tid & 31;
      float inv = 0.125f / Lr[r];
      #pragma unroll 2
      for (int it = 0; it < 8; ++it){
        int c = jl*4 + it*128;
        f32x4 e = *(f32x4*)&S[r][c];
        if (e[0] != 0.f || e[1] != 0.f || e[2] != 0.f || e[3] != 0.f){
          f32x4 a0 = *(f32x4*)&AM[r][c];
          a0 += e * inv;
          *(f32x4*)&AM[r][c] = a0;
        }
      }
    }
    // ---- PV: wave owns K-range of 128, o = sum e*v (normalize at end) ----
    f32x4 oa0 = {0.f,0.f,0.f,0.f}, oa1 = {0.f,0.f,0.f,0.f};
    { int kb0 = wave * 128;
      #pragma unroll
      for (int kk = 0; kk < 4; ++kk){
        int kb2 = kb0 + kk*32 + agrp*8;
        f32x4 p0 = *(f32x4*)&S[arow][kb2];
        f32x4 p1 = *(f32x4*)&S[arow][kb2 + 4];
        u32x4 pw;
        pw[0] = (u32)f2bf(p0[0]) | ((u32)f2bf(p0[1]) << 16);
        pw[1] = (u32)f2bf(p0[2]) | ((u32)f2bf(p0[3]) << 16);
        pw[2] = (u32)f2bf(p1[0]) | ((u32)f2bf(p1[1]) << 16);
        pw[3] = (u32)f2bf(p1[2]) | ((u32)f2bf(p1[3]) << 16);
        bf16x8 pf; __builtin_memcpy(&pf, &pw, 16);
        bf16x8 v0 = ld_bf8(vp + (long)(h*HDd +      arow) * Nn + kb0 + kk*32 + agrp*8);
        bf16x8 v1 = ld_bf8(vp + (long)(h*HDd + 16 + arow) * Nn + kb0 + kk*32 + agrp*8);
        oa0 = mfma16(pf, v0, oa0);
        oa1 = mfma16(pf, v1, oa1);
      }
    }
    __syncthreads();
    // ---- reduce o across waves (reuse S as [8][16][32]) ----
    float* ored = &S[0][0];
    #pragma unroll
    for (int r = 0; r < 4; ++r){
      ored[(wave*16 + agrp*4 + r)*32 + arow]      = oa0[r];
      ored[(wave*16 + agrp*4 + r)*32 + 16 + arow] = oa1[r];
    }
    __syncthreads();
    { int rr = tid >> 5, cc = tid & 31;
      float ssum = 0.f;
      #pragma unroll
      for (int w2 = 0; w2 < 8; ++w2) ssum += ored[(w2*16 + rr)*32 + cc];
      ssum /= Lr[rr];
      o[((long)b * Nn + i0 + rr) * Dd + h*HDd + cc] = f2bf(ssum);
    }
  }
  __syncthreads();
  // ---- write a_mean (bf16), optionally transposed (layer 0 seeds chain^T) ----
  if (!transposed){
    int r = tid >> 5, jl = tid & 31;
    #pragma unroll
    for (int it = 0; it < 4; ++it){
      int c = jl*8 + it*256;
      u32x4 wv;
      #pragma unroll
      for (int p = 0; p < 4; ++p)
        wv[p] = (u32)f2bf(AM[r][c + 2*p]) | ((u32)f2bf(AM[r][c + 2*p + 1]) << 16);
      *(u32x4*)(am + (long)b*Nn*Nn + (long)(i0 + r)*Nn + c) = wv;
    }
  } else {
    for (int j = tid; j < Nn; j += 512){
      u32x4 lo, hi;
      #pragma unroll
      for (int p = 0; p < 4; ++p){
        lo[p] = (u32)f2bf(AM[2*p    ][j]) | ((u32)f2bf(AM[2*p + 1][j]) << 16);
        hi[p] = (u32)f2bf(AM[2*p + 8][j]) | ((u32)f2bf(AM[2*p + 9][j]) << 16);
      }
      u16* dst = am + (long)b*Nn*Nn + (long)j*Nn + i0;
      *(u32x4*)dst = lo; *(u32x4*)(dst + 8) = hi;
    }
  }
}

// ---------------- residual + layernorm ----------------
__global__ __launch_bounds__(256) void ln_kernel(
    const float* __restrict__ hin, const float* __restrict__ y,
    float* __restrict__ hout, u16* __restrict__ hb, float* __restrict__ outf,
    const float* __restrict__ g, const float* __restrict__ be)
{
  int row  = blockIdx.x * 4 + (threadIdx.x >> 6);
  int lane = threadIdx.x & 63;
  f32x4 v = *(const f32x4*)(hin + (long)row*Dd + lane*4)
          + *(const f32x4*)(y   + (long)row*Dd + lane*4);
  float s = v[0] + v[1] + v[2] + v[3];
  #pragma unroll
  for (int off = 32; off; off >>= 1) s += __shfl_xor(s, off, 64);
  float mu = s * (1.f/256.f);
  f32x4 d = v - mu;
  float q2 = d[0]*d[0] + d[1]*d[1] + d[2]*d[2] + d[3]*d[3];
  #pragma unroll
  for (int off = 32; off; off >>= 1) q2 += __shfl_xor(q2, off, 64);
  float rs = rsqrtf(q2 * (1.f/256.f) + 1e-5f);
  f32x4 ov;
  #pragma unroll
  for (int p = 0; p < 4; ++p)
    ov[p] = d[p] * rs * g[lane*4 + p] + be[lane*4 + p];
  *(f32x4*)(hout + (long)row*Dd + lane*4) = ov;
  if (hb){
    u32x2 pb;
    pb[0] = (u32)f2bf(ov[0]) | ((u32)f2bf(ov[1]) << 16);
    pb[1] = (u32)f2bf(ov[2]) | ((u32)f2bf(ov[3]) << 16);
    *(u32x2*)(hb + (long)row*Dd + lane*4) = pb;
  }
  if (outf)
    *(f32x4*)(outf + (long)row*Dd + lane*4) = ov;
}

extern "C" void kernel_launch(void* const* d_in, const int* in_sizes, int n_in,
                              void* d_out, int out_size, void* d_ws, size_t ws_size,
                              hipStream_t stream)
{
  (void)in_sizes; (void)n_in; (void)out_size; (void)ws_size;
  const float* x   = (const float*)d_in[0];
  const float* adj = (const float*)d_in[1];
  const float* W0  = (const float*)d_in[2];
  const float* Wq  = (const float*)d_in[3];
  const float* bq  = (const float*)d_in[4];
  const float* Wk  = (const float*)d_in[5];
  const float* bk  = (const float*)d_in[6];
  const float* Wv  = (const float*)d_in[7];
  const float* bv  = (const float*)d_in[8];
  const float* Wo  = (const float*)d_in[9];
  const float* bo  = (const float*)d_in[10];
  const float* gm  = (const float*)d_in[11];
  const float* bt  = (const float*)d_in[12];
  float* outf  = (float*)d_out;                 // f32 h region [8,1024,256]
  float* outat = outf + (long)Bb * Nn * Dd;     // f32 atten region [8,1024,1024]
  const long NN = (long)Nn * Nn;

  // ---- workspace (~89.8MB < proven 92MB) ----
  char* w = (char*)d_ws;
  u16* W0b = (u16*)w; w += 131072;
  u16* Wqb = (u16*)w; w += 393216;
  u16* Wkb = (u16*)w; w += 393216;
  u16* Wvb = (u16*)w; w += 393216;
  u16* Wob = (u16*)w; w += 393216;
  u32* bitsg = (u32*)w; w += 131072;
  u16* xb  = (u16*)w; w += 4194304;
  u16* hb  = (u16*)w; w += 4194304;
  u16* qb  = (u16*)w; w += 4194304;
  u16* kb  = (u16*)w; w += 4194304;
  u16* vt  = (u16*)w; w += 4194304;
  u16* ob  = (u16*)w; w += 4194304;
  float* hbuf = (float*)w; w += 8388608;
  float* ybuf = (float*)w; w += 8388608;
  u16* amA = (u16*)w; w += 16777216;   // am0^T, later am2
  u16* amB = (u16*)w; w += 16777216;   // am1
  u16* amC = (u16*)w; w += 16777216;   // P1^T

  dim3 blk(256);
  f32_to_bf16<<<2048, blk, 0, stream>>>(x,  xb,  2097152);
  f32_to_bf16<<<64,   blk, 0, stream>>>(W0, W0b, 65536);
  f32_to_bf16<<<192,  blk, 0, stream>>>(Wq, Wqb, 196608);
  f32_to_bf16<<<192,  blk, 0, stream>>>(Wk, Wkb, 196608);
  f32_to_bf16<<<192,  blk, 0, stream>>>(Wv, Wvb, 196608);
  f32_to_bf16<<<192,  blk, 0, stream>>>(Wo, Wob, 196608);
  adj_to_bits<<<128, blk, 0, stream>>>(adj, bitsg);

  // input projection: h = x @ W0^T  (f32 + bf16)
  gemm_bt<false,false,true,true><<<dim3(2,64,1), blk, 0, stream>>>(
      xb, 256, 0, W0b, 256, 0, hbuf, hb, 256, 0, 256, nullptr, nullptr);

  for (int l = 0; l < 3; ++l){
    const u16* wq = Wqb + (long)l*65536;
    const u16* wk = Wkb + (long)l*65536;
    const u16* wv = Wvb + (long)l*65536;
    const u16* wo = Wob + (long)l*65536;
    gemm_bt<true,false,false,true><<<dim3(2,64,1), blk, 0, stream>>>(
        hb, 256, 0, wq, 256, 0, nullptr, qb, 256, 0, 256, bq + l*256, nullptr);
    gemm_bt<true,false,false,true><<<dim3(2,64,1), blk, 0, stream>>>(
        hb, 256, 0, wk, 256, 0, nullptr, kb, 256, 0, 256, bk + l*256, nullptr);
    // vT[b][e][n] = Wv[e][:] . h[b][n][:] + bv[e]
    gemm_bt<false,true,false,true><<<dim3(8,2,8), blk, 0, stream>>>(
        wv, 256, 0, hb, 256, (long)Nn*Dd, nullptr, vt, 1024, (long)Dd*Nn, 256,
        nullptr, bv + l*256);
    // fused attention; am dst: l0 -> amA (transposed), l1 -> amB, l2 -> amA
    attn_kernel<<<dim3(64,8), dim3(512), 0, stream>>>(
        qb, kb, vt, ob, bitsg, (l == 1 ? amB : amA), (l == 0) ? 1 : 0);
    // y = o @ Wo^T + bo (f32)
    gemm_bt<true,false,true,false><<<dim3(2,64,1), blk, 0, stream>>>(
        ob, 256, 0, wo, 256, 0, ybuf, nullptr, 256, 0, 256, bo + l*256, nullptr);
    // h = LN(h + y): f32 hbuf (+ bf16 hb interior, f32 d_out final)
    ln_kernel<<<dim3(2048), blk, 0, stream>>>(
        hbuf, ybuf, hbuf, (l < 2 ? hb : nullptr), (l < 2 ? nullptr : outf),
        gm + l*256, bt + l*256);
    // chain: l1: P1^T = (am1@am0)^T -> amC (bf16); l2: final = am2@P1 -> f32 d_out
    if (l == 1)
      gemm_bt<false,false,false,true><<<dim3(8,8,8), blk, 0, stream>>>(
          amA, 1024, NN, amB, 1024, NN, nullptr, amC, 1024, NN, 1024, nullptr, nullptr);
    if (l == 2)
      gemm_bt<false,false,true,false><<<dim3(8,8,8), blk, 0, stream>>>(
          amA, 1024, NN, amC, 1024, NN, outat, nullptr, 1024, NN, 1024, nullptr, nullptr);
  }
}

// Round 6
// 435.612 us; speedup vs baseline: 6.2890x; 1.6082x over previous
//
#include <hip/hip_runtime.h>

typedef unsigned short u16;
typedef unsigned int   u32;
typedef float  f32x4  __attribute__((ext_vector_type(4)));
typedef __bf16 bf16x8 __attribute__((ext_vector_type(8)));
typedef u32    u32x4  __attribute__((ext_vector_type(4)));
typedef u32    u32x2  __attribute__((ext_vector_type(2)));

#define Bb  8
#define Nn  1024
#define Dd  256
#define Hh  8
#define HDd 32

__device__ __forceinline__ u16 f2bf(float f){
  u32 u; __builtin_memcpy(&u, &f, 4);
  u = (u + 0x7fffu + ((u >> 16) & 1u)) >> 16;
  return (u16)u;
}
__device__ __forceinline__ f32x4 mfma16(bf16x8 a, bf16x8 b, f32x4 c){
  return __builtin_amdgcn_mfma_f32_16x16x32_bf16(a, b, c, 0, 0, 0);
}
__device__ __forceinline__ bf16x8 ld_bf8(const u16* p){
  u32x4 u = *(const u32x4*)p; bf16x8 r; __builtin_memcpy(&r, &u, 16); return r;
}

// ---------------- f32 -> bf16 convert ----------------
__global__ void f32_to_bf16(const float* __restrict__ src, u16* __restrict__ dst, int n){
  int i = (blockIdx.x * 256 + threadIdx.x) * 4;
  if (i < n){
    f32x4 v = *(const f32x4*)(src + i);
    u32x2 p;
    p[0] = (u32)f2bf(v[0]) | ((u32)f2bf(v[1]) << 16);
    p[1] = (u32)f2bf(v[2]) | ((u32)f2bf(v[3]) << 16);
    *(u32x2*)(dst + i) = p;
  }
}

// ---------------- adj -> bitmask ----------------
__global__ void adj_to_bits(const float* __restrict__ adj, u32* __restrict__ bits){
  int w = blockIdx.x * 256 + threadIdx.x;        // word over [1024][32]
  const float* p = adj + (long)w * 32;
  u32 m = 0;
  #pragma unroll
  for (int t = 0; t < 32; t += 4){
    f32x4 v = *(const f32x4*)(p + t);
    if (v[0] != 0.f) m |= 1u << (t+0);
    if (v[1] != 0.f) m |= 1u << (t+1);
    if (v[2] != 0.f) m |= 1u << (t+2);
    if (v[3] != 0.f) m |= 1u << (t+3);
  }
  bits[w] = m;
}

// ---------------- MFMA GEMM: C[m][n] = sum_k A[m][k]*Bt[n][k] (+bias) ----------------
// VALIDATED (R4): bf16 and f32 epilogues both correct.
template<bool HBC, bool HBR, bool OF, bool OB>
__global__ __launch_bounds__(256,2) void gemm_bt(
    const u16* __restrict__ A, int lda, long sA,
    const u16* __restrict__ Bt, int ldb, long sB,
    float* __restrict__ Cf, u16* __restrict__ Cb, int ldc, long sC,
    int K, const float* __restrict__ bc, const float* __restrict__ br)
{
  __shared__ u16 As[128][40];
  __shared__ u16 Bs[128][40];
  const int bz = blockIdx.z;
  const u16* Ap = A + (long)bz * sA;
  const u16* Bp = Bt + (long)bz * sB;
  const long co = (long)bz * sC;
  const int m0 = blockIdx.y * 128, n0 = blockIdx.x * 128;
  const int tid = threadIdx.x, wave = tid >> 6, lane = tid & 63;
  const int arow = lane & 15, agrp = lane >> 4;
  const int wr = (wave >> 1) * 64, wc = (wave & 1) * 64;
  const int srow = tid >> 1, sch = (tid & 1) * 16;
  const u16* ga = Ap + (long)(m0 + srow) * lda + sch;
  const u16* gb = Bp + (long)(n0 + srow) * ldb + sch;
  f32x4 acc[4][4] = {};
  for (int kb = 0; kb < K; kb += 32){
    u32x4 a0 = *(const u32x4*)ga; u32x4 a1 = *(const u32x4*)(ga + 8);
    u32x4 b0 = *(const u32x4*)gb; u32x4 b1 = *(const u32x4*)(gb + 8);
    __syncthreads();
    *(u32x4*)&As[srow][sch] = a0; *(u32x4*)&As[srow][sch + 8] = a1;
    *(u32x4*)&Bs[srow][sch] = b0; *(u32x4*)&Bs[srow][sch + 8] = b1;
    __syncthreads();
    ga += 32; gb += 32;
    bf16x8 af[4], bv[4];
    #pragma unroll
    for (int f = 0; f < 4; ++f){
      af[f] = ld_bf8(&As[wr + f*16 + arow][agrp*8]);
      bv[f] = ld_bf8(&Bs[wc + f*16 + arow][agrp*8]);
    }
    #pragma unroll
    for (int fm = 0; fm < 4; ++fm)
      #pragma unroll
      for (int fn = 0; fn < 4; ++fn)
        acc[fm][fn] = mfma16(af[fm], bv[fn], acc[fm][fn]);
  }
  #pragma unroll
  for (int fm = 0; fm < 4; ++fm){
    #pragma unroll
    for (int fn = 0; fn < 4; ++fn){
      int j = n0 + wc + fn*16 + arow;
      float badd = 0.f;
      if (HBC) badd = bc[j];
      #pragma unroll
      for (int r = 0; r < 4; ++r){
        int i = m0 + wr + fm*16 + agrp*4 + r;
        float v = acc[fm][fn][r] + badd;
        if (HBR) v += br[i];
        long idx = co + (long)i * ldc + j;
        if (OF) Cf[idx] = v;
        if (OB) Cb[idx] = f2bf(v);
      }
    }
  }
}

// ---------------- fused masked attention v2 ----------------
// per (b, 16-row tile); AM accumulator in registers; sparse softmax.
#define NPAD 1036
__global__ __launch_bounds__(512,4) void attn_kernel(
    const u16* __restrict__ q, const u16* __restrict__ k,
    const u16* __restrict__ vT, u16* __restrict__ o,
    const u32* __restrict__ bitsg, u16* __restrict__ am, int transposed)
{
  __shared__ float S[16][NPAD];      // scores -> exp values (75KB total LDS)
  __shared__ u16   qs[16][264];
  __shared__ u32   bits[16][32];

  const int b = blockIdx.y, i0 = blockIdx.x * 16;
  const int tid = threadIdx.x, wave = tid >> 6, lane = tid & 63;
  const int arow = lane & 15, agrp = lane >> 4;
  const int r = tid >> 5, jl = tid & 31;      // softmax/epilogue grouping
  const float SCALE = 0.17677669529663687f;   // 1/sqrt(32)
  const u16* qp = q  + ((long)b * Nn + i0) * Dd;
  const u16* kp = k  + (long)b * Nn * Dd;
  const u16* vp = vT + (long)b * Dd * Nn;

  { int rr = tid >> 5, c = (tid & 31) * 8;
    *(u32x4*)&qs[rr][c] = *(const u32x4*)(qp + (long)rr * Dd + c); }
  bits[r][jl] = bitsg[(long)(i0 + r) * 32 + jl];

  f32x4 amreg[8] = {};                        // AM[r][jl*4 + it*128], it=0..7
  const f32x4 zacc = {0.f, 0.f, 0.f, 0.f};

  for (int h = 0; h < Hh; ++h){
    __syncthreads();                       // prev consumers of S done; loads visible
    // ---- S fill: wave covers 8 j-tiles of 16 ----
    bf16x8 afr = ld_bf8(&qs[arow][h * HDd + agrp * 8]);
    #pragma unroll
    for (int s = 0; s < 8; ++s){
      int j0 = (wave * 8 + s) * 16;
      bf16x8 bfr = ld_bf8(kp + (long)(j0 + arow) * Dd + h * HDd + agrp * 8);
      f32x4 c = mfma16(afr, bfr, zacc);
      #pragma unroll
      for (int rr = 0; rr < 4; ++rr) S[agrp*4 + rr][j0 + arow] = c[rr] * SCALE;
    }
    __syncthreads();
    // ---- sparse max: thread owns bit-word jl (~1 set bit avg) ----
    float mx = -3.0e38f;
    { u32 wd = bits[r][jl];
      while (wd){
        int bi = __ffs(wd) - 1; wd &= wd - 1;
        mx = fmaxf(mx, S[r][jl*32 + bi]);
      }
    }
    #pragma unroll
    for (int off = 16; off; off >>= 1) mx = fmaxf(mx, __shfl_xor(mx, off, 32));
    // ---- sparse sum ----
    float l = 0.f;
    { u32 wd = bits[r][jl];
      while (wd){
        int bi = __ffs(wd) - 1; wd &= wd - 1;
        l += __expf(S[r][jl*32 + bi] - mx);
      }
    }
    #pragma unroll
    for (int off = 16; off; off >>= 1) l += __shfl_xor(l, off, 32);
    float invl = 1.f / l, inv8 = 0.125f * invl;
    // ---- vectorized exp/zero write + fused AM accumulate (nibble skip) ----
    #pragma unroll
    for (int it = 0; it < 8; ++it){
      int c = jl*4 + it*128;
      u32 nib = (bits[r][(jl >> 3) + it*4] >> ((jl & 7) * 4)) & 0xFu;
      f32x4 e = {0.f, 0.f, 0.f, 0.f};
      if (nib){
        f32x4 sv = *(f32x4*)&S[r][c];
        if (nib & 1u) e[0] = __expf(sv[0] - mx);
        if (nib & 2u) e[1] = __expf(sv[1] - mx);
        if (nib & 4u) e[2] = __expf(sv[2] - mx);
        if (nib & 8u) e[3] = __expf(sv[3] - mx);
        amreg[it] += e * inv8;
      }
      *(f32x4*)&S[r][c] = e;
    }
    __syncthreads();
    // ---- PV: wave owns K-range of 128 ----
    f32x4 oa0 = {0.f,0.f,0.f,0.f}, oa1 = {0.f,0.f,0.f,0.f};
    { int kb0 = wave * 128;
      #pragma unroll
      for (int kk = 0; kk < 4; ++kk){
        int kb2 = kb0 + kk*32 + agrp*8;
        f32x4 p0 = *(f32x4*)&S[arow][kb2];
        f32x4 p1 = *(f32x4*)&S[arow][kb2 + 4];
        u32x4 pw;
        pw[0] = (u32)f2bf(p0[0]) | ((u32)f2bf(p0[1]) << 16);
        pw[1] = (u32)f2bf(p0[2]) | ((u32)f2bf(p0[3]) << 16);
        pw[2] = (u32)f2bf(p1[0]) | ((u32)f2bf(p1[1]) << 16);
        pw[3] = (u32)f2bf(p1[2]) | ((u32)f2bf(p1[3]) << 16);
        bf16x8 pf; __builtin_memcpy(&pf, &pw, 16);
        bf16x8 v0 = ld_bf8(vp + (long)(h*HDd +      arow) * Nn + kb0 + kk*32 + agrp*8);
        bf16x8 v1 = ld_bf8(vp + (long)(h*HDd + 16 + arow) * Nn + kb0 + kk*32 + agrp*8);
        oa0 = mfma16(pf, v0, oa0);
        oa1 = mfma16(pf, v1, oa1);
      }
    }
    __syncthreads();
    // ---- reduce o across waves (reuse S as [8][16][32]) ----
    float* ored = &S[0][0];
    #pragma unroll
    for (int rr = 0; rr < 4; ++rr){
      ored[(wave*16 + agrp*4 + rr)*32 + arow]      = oa0[rr];
      ored[(wave*16 + agrp*4 + rr)*32 + 16 + arow] = oa1[rr];
    }
    __syncthreads();
    { float ssum = 0.f;
      #pragma unroll
      for (int w2 = 0; w2 < 8; ++w2) ssum += ored[(w2*16 + r)*32 + jl];
      ssum *= invl;
      o[((long)b * Nn + i0 + r) * Dd + h*HDd + jl] = f2bf(ssum);
    }
  }
  // ---- stage AM regs -> S, then write a_mean (bf16) ----
  __syncthreads();
  #pragma unroll
  for (int it = 0; it < 8; ++it)
    *(f32x4*)&S[r][jl*4 + it*128] = amreg[it];
  __syncthreads();
  if (!transposed){
    #pragma unroll
    for (int it = 0; it < 4; ++it){
      int c = jl*8 + it*256;
      u32x4 wv;
      #pragma unroll
      for (int p = 0; p < 4; ++p)
        wv[p] = (u32)f2bf(S[r][c + 2*p]) | ((u32)f2bf(S[r][c + 2*p + 1]) << 16);
      *(u32x4*)(am + (long)b*Nn*Nn + (long)(i0 + r)*Nn + c) = wv;
    }
  } else {
    for (int j = tid; j < Nn; j += 512){
      u32x4 lo, hi;
      #pragma unroll
      for (int p = 0; p < 4; ++p){
        lo[p] = (u32)f2bf(S[2*p    ][j]) | ((u32)f2bf(S[2*p + 1][j]) << 16);
        hi[p] = (u32)f2bf(S[2*p + 8][j]) | ((u32)f2bf(S[2*p + 9][j]) << 16);
      }
      u16* dst = am + (long)b*Nn*Nn + (long)j*Nn + i0;
      *(u32x4*)dst = lo; *(u32x4*)(dst + 8) = hi;
    }
  }
}

// ---------------- residual + layernorm ----------------
__global__ __launch_bounds__(256) void ln_kernel(
    const float* __restrict__ hin, const float* __restrict__ y,
    float* __restrict__ hout, u16* __restrict__ hb, float* __restrict__ outf,
    const float* __restrict__ g, const float* __restrict__ be)
{
  int row  = blockIdx.x * 4 + (threadIdx.x >> 6);
  int lane = threadIdx.x & 63;
  f32x4 v = *(const f32x4*)(hin + (long)row*Dd + lane*4)
          + *(const f32x4*)(y   + (long)row*Dd + lane*4);
  float s = v[0] + v[1] + v[2] + v[3];
  #pragma unroll
  for (int off = 32; off; off >>= 1) s += __shfl_xor(s, off, 64);
  float mu = s * (1.f/256.f);
  f32x4 d = v - mu;
  float q2 = d[0]*d[0] + d[1]*d[1] + d[2]*d[2] + d[3]*d[3];
  #pragma unroll
  for (int off = 32; off; off >>= 1) q2 += __shfl_xor(q2, off, 64);
  float rs = rsqrtf(q2 * (1.f/256.f) + 1e-5f);
  f32x4 ov;
  #pragma unroll
  for (int p = 0; p < 4; ++p)
    ov[p] = d[p] * rs * g[lane*4 + p] + be[lane*4 + p];
  *(f32x4*)(hout + (long)row*Dd + lane*4) = ov;
  if (hb){
    u32x2 pb;
    pb[0] = (u32)f2bf(ov[0]) | ((u32)f2bf(ov[1]) << 16);
    pb[1] = (u32)f2bf(ov[2]) | ((u32)f2bf(ov[3]) << 16);
    *(u32x2*)(hb + (long)row*Dd + lane*4) = pb;
  }
  if (outf)
    *(f32x4*)(outf + (long)row*Dd + lane*4) = ov;
}

extern "C" void kernel_launch(void* const* d_in, const int* in_sizes, int n_in,
                              void* d_out, int out_size, void* d_ws, size_t ws_size,
                              hipStream_t stream)
{
  (void)in_sizes; (void)n_in; (void)out_size; (void)ws_size;
  const float* x   = (const float*)d_in[0];
  const float* adj = (const float*)d_in[1];
  const float* W0  = (const float*)d_in[2];
  const float* Wq  = (const float*)d_in[3];
  const float* bq  = (const float*)d_in[4];
  const float* Wk  = (const float*)d_in[5];
  const float* bk  = (const float*)d_in[6];
  const float* Wv  = (const float*)d_in[7];
  const float* bv  = (const float*)d_in[8];
  const float* Wo  = (const float*)d_in[9];
  const float* bo  = (const float*)d_in[10];
  const float* gm  = (const float*)d_in[11];
  const float* bt  = (const float*)d_in[12];
  float* outf  = (float*)d_out;                 // f32 h region [8,1024,256]
  float* outat = outf + (long)Bb * Nn * Dd;     // f32 atten region [8,1024,1024]
  const long NN = (long)Nn * Nn;

  // ---- workspace (~89.8MB < proven 92MB) ----
  char* w = (char*)d_ws;
  u16* W0b = (u16*)w; w += 131072;
  u16* Wqb = (u16*)w; w += 393216;
  u16* Wkb = (u16*)w; w += 393216;
  u16* Wvb = (u16*)w; w += 393216;
  u16* Wob = (u16*)w; w += 393216;
  u32* bitsg = (u32*)w; w += 131072;
  u16* xb  = (u16*)w; w += 4194304;
  u16* hb  = (u16*)w; w += 4194304;
  u16* qb  = (u16*)w; w += 4194304;
  u16* kb  = (u16*)w; w += 4194304;
  u16* vt  = (u16*)w; w += 4194304;
  u16* ob  = (u16*)w; w += 4194304;
  float* hbuf = (float*)w; w += 8388608;
  float* ybuf = (float*)w; w += 8388608;
  u16* amA = (u16*)w; w += 16777216;   // am0^T, later am2
  u16* amB = (u16*)w; w += 16777216;   // am1
  u16* amC = (u16*)w; w += 16777216;   // P1^T

  dim3 blk(256);
  f32_to_bf16<<<2048, blk, 0, stream>>>(x,  xb,  2097152);
  f32_to_bf16<<<64,   blk, 0, stream>>>(W0, W0b, 65536);
  f32_to_bf16<<<192,  blk, 0, stream>>>(Wq, Wqb, 196608);
  f32_to_bf16<<<192,  blk, 0, stream>>>(Wk, Wkb, 196608);
  f32_to_bf16<<<192,  blk, 0, stream>>>(Wv, Wvb, 196608);
  f32_to_bf16<<<192,  blk, 0, stream>>>(Wo, Wob, 196608);
  adj_to_bits<<<128, blk, 0, stream>>>(adj, bitsg);

  // input projection: h = x @ W0^T  (f32 + bf16)
  gemm_bt<false,false,true,true><<<dim3(2,64,1), blk, 0, stream>>>(
      xb, 256, 0, W0b, 256, 0, hbuf, hb, 256, 0, 256, nullptr, nullptr);

  for (int l = 0; l < 3; ++l){
    const u16* wq = Wqb + (long)l*65536;
    const u16* wk = Wkb + (long)l*65536;
    const u16* wv = Wvb + (long)l*65536;
    const u16* wo = Wob + (long)l*65536;
    gemm_bt<true,false,false,true><<<dim3(2,64,1), blk, 0, stream>>>(
        hb, 256, 0, wq, 256, 0, nullptr, qb, 256, 0, 256, bq + l*256, nullptr);
    gemm_bt<true,false,false,true><<<dim3(2,64,1), blk, 0, stream>>>(
        hb, 256, 0, wk, 256, 0, nullptr, kb, 256, 0, 256, bk + l*256, nullptr);
    // vT[b][e][n] = Wv[e][:] . h[b][n][:] + bv[e]
    gemm_bt<false,true,false,true><<<dim3(8,2,8), blk, 0, stream>>>(
        wv, 256, 0, hb, 256, (long)Nn*Dd, nullptr, vt, 1024, (long)Dd*Nn, 256,
        nullptr, bv + l*256);
    // fused attention; am dst: l0 -> amA (transposed), l1 -> amB, l2 -> amA
    attn_kernel<<<dim3(64,8), dim3(512), 0, stream>>>(
        qb, kb, vt, ob, bitsg, (l == 1 ? amB : amA), (l == 0) ? 1 : 0);
    // y = o @ Wo^T + bo (f32)
    gemm_bt<true,false,true,false><<<dim3(2,64,1), blk, 0, stream>>>(
        ob, 256, 0, wo, 256, 0, ybuf, nullptr, 256, 0, 256, bo + l*256, nullptr);
    // h = LN(h + y): f32 hbuf (+ bf16 hb interior, f32 d_out final)
    ln_kernel<<<dim3(2048), blk, 0, stream>>>(
        hbuf, ybuf, hbuf, (l < 2 ? hb : nullptr), (l < 2 ? nullptr : outf),
        gm + l*256, bt + l*256);
    // chain: l1: P1^T = (am1@am0)^T -> amC (bf16); l2: final = am2@P1 -> f32 d_out
    if (l == 1)
      gemm_bt<false,false,false,true><<<dim3(8,8,8), blk, 0, stream>>>(
          amA, 1024, NN, amB, 1024, NN, nullptr, amC, 1024, NN, 1024, nullptr, nullptr);
    if (l == 2)
      gemm_bt<false,false,true,false><<<dim3(8,8,8), blk, 0, stream>>>(
          amA, 1024, NN, amC, 1024, NN, outat, nullptr, 1024, NN, 1024, nullptr, nullptr);
  }
}